// Round 6
// baseline (57.943 us; speedup 1.0000x reference)
//
#include <hip/hip_runtime.h>
#include <cstdint>
#include <cstddef>

#define SEQD 20
#define HID  512
#define LSEQ 2048
#define MROWS 8192
#define GBM 128
#define GBN 128
#define GBK 64
#define ITILE 16
#define HPART_FLOATS (8u * MROWS * 8u)   // [slice=8][8192][8]

typedef __attribute__((ext_vector_type(4))) float f32x4;
typedef __attribute__((ext_vector_type(8))) short bf16x8;

__device__ __forceinline__ ushort f2bf(float f) {
  union { float f; unsigned u; } v; v.f = f;
  unsigned r = v.u + 0x7fffu + ((v.u >> 16) & 1u);   // RNE
  return (ushort)(r >> 16);
}
// XOR-swizzle of byte offset b (0..127) within a 128B k-stripe, keyed by row.
// Involution on 16B-slot bits (4..6). Applied at global write (pre-swizzle)
// and at ds_read; LDS staging copies linearly (rule #21).
__device__ __forceinline__ int swzb(int row, int b) {
  return (b & 0x0F) | ((b ^ ((row & 7) << 4)) & 0x70);
}
// async global->LDS, 16B/lane. lds ptr wave-uniform (HW adds lane*16).
__device__ __forceinline__ void async16(const ushort* g, ushort* l) {
  __builtin_amdgcn_global_load_lds(
      (const __attribute__((address_space(1))) unsigned*)g,
      (__attribute__((address_space(3))) unsigned*)l, 16, 0, 0);
}

// ---------------------------------------------------------------------------
// Kernel 1 (prep): blocks [0,512): h1 = relu(X@W1+b1) -> bf16, PRE-SWIZZLED.
//                  blocks [512,768): W2t[n][k] bf16 transpose, PRE-SWIZZLED.
// ---------------------------------------------------------------------------
__global__ __launch_bounds__(256) void k_prep(const float* __restrict__ X,
                                              const float* __restrict__ W1,
                                              const float* __restrict__ b1,
                                              const float* __restrict__ W2,
                                              ushort* __restrict__ h1,
                                              ushort* __restrict__ W2t) {
  __shared__ float Xs[16][SEQD + 1];
  __shared__ float tile[32][33];
  const int t = threadIdx.x;
  if (blockIdx.x < 512) {
    const int base = blockIdx.x * 16;
    for (int i = t; i < 16 * SEQD; i += 256) Xs[i / SEQD][i % SEQD] = X[base * SEQD + i];
    __syncthreads();
    const int m0 = (t >> 6) * 4;
    const int nl = (t & 63) * 4;
    float4 acc[4][2];
#pragma unroll
    for (int mi = 0; mi < 4; ++mi) {
      acc[mi][0] = *(const float4*)&b1[nl];
      acc[mi][1] = *(const float4*)&b1[nl + 256];
    }
#pragma unroll
    for (int k = 0; k < SEQD; ++k) {
      const float4 w0 = *(const float4*)&W1[k * HID + nl];
      const float4 w1 = *(const float4*)&W1[k * HID + nl + 256];
#pragma unroll
      for (int mi = 0; mi < 4; ++mi) {
        const float xv = Xs[m0 + mi][k];
        acc[mi][0].x += xv * w0.x; acc[mi][0].y += xv * w0.y;
        acc[mi][0].z += xv * w0.z; acc[mi][0].w += xv * w0.w;
        acc[mi][1].x += xv * w1.x; acc[mi][1].y += xv * w1.y;
        acc[mi][1].z += xv * w1.z; acc[mi][1].w += xv * w1.w;
      }
    }
#pragma unroll
    for (int mi = 0; mi < 4; ++mi) {
      const int m = base + m0 + mi;
#pragma unroll
      for (int g = 0; g < 2; ++g) {
        const float4 r = acc[mi][g];
        ushort4 o;
        o.x = f2bf(fmaxf(r.x, 0.f)); o.y = f2bf(fmaxf(r.y, 0.f));
        o.z = f2bf(fmaxf(r.z, 0.f)); o.w = f2bf(fmaxf(r.w, 0.f));
        const int k = nl + g * 256;
        const int sb = swzb(m, (k & 63) * 2);
        *(ushort4*)&h1[(size_t)m * HID + (k & ~63) + (sb >> 1)] = o;
      }
    }
  } else {
    const int c = blockIdx.x - 512;
    const int k0 = (c & 15) * 32, n0 = (c >> 4) * 32;
    const int tx = t & 31, ty = t >> 5;
#pragma unroll
    for (int r = ty; r < 32; r += 8)
      tile[r][tx] = W2[(size_t)(k0 + r) * HID + n0 + tx];
    __syncthreads();
#pragma unroll
    for (int r = ty; r < 32; r += 8) {
      const int n = n0 + r, k = k0 + tx;
      const int sb = swzb(n, (k & 63) * 2);
      W2t[(size_t)n * HID + (k & ~63) + (sb >> 1)] = f2bf(tile[tx][r]);
    }
  }
}

// ---------------------------------------------------------------------------
// Kernel 2: gemm2 + fused heads — EXACT R4 config (faster of R4/R5 A/B):
// BM=BN=128, BK=64, grid 256, 4 waves 2x2, 2-phase dbuf global_load_lds.
// Hpart: [slice=8][8192][8] f32; slice = xblk*2 + wc.
// ---------------------------------------------------------------------------
__global__ __launch_bounds__(256) void k_gemm_heads(const ushort* __restrict__ Aglob,
                                                    const ushort* __restrict__ Bglob,
                                                    const float* __restrict__ b2,
                                                    const float* __restrict__ Wss,
                                                    const float* __restrict__ Wang,
                                                    const float* __restrict__ Wc,
                                                    float* __restrict__ Hpart) {
  __shared__ ushort As[2][GBM * GBK];
  __shared__ ushort Bs[2][GBM * GBK];
  const int t = threadIdx.x;
  const int wave = t >> 6, lane = t & 63;
  const int l15 = lane & 15, lhi = lane >> 4;
  const int wr = wave >> 1, wc = wave & 1;
  const int swz = (blockIdx.x & 7) * 32 + (blockIdx.x >> 3);  // bijective, 256%8==0
  const int xblk = swz & 3, yblk = swz >> 2;
  const int bm = yblk * GBM, bn = xblk * GBN;
  const int srow = lane >> 3;
  const int scol = (lane & 7) * 8;

  f32x4 acc[4][4];
#pragma unroll
  for (int mi = 0; mi < 4; ++mi)
#pragma unroll
    for (int ni = 0; ni < 4; ++ni) acc[mi][ni] = {0.f, 0.f, 0.f, 0.f};

#define STAGE(buf, k0)                                                         \
  {                                                                            \
    _Pragma("unroll")                                                          \
    for (int rd = 0; rd < 4; ++rd) {                                           \
      const int r = rd * 32 + wave * 8 + srow;                                 \
      const int lo = rd * 2048 + wave * 512;                                   \
      async16(Aglob + (size_t)(bm + r) * HID + (k0) + scol, &As[buf][lo]);     \
      async16(Bglob + (size_t)(bn + r) * HID + (k0) + scol, &Bs[buf][lo]);     \
    }                                                                          \
  }

#define COMPUTE(buf)                                                           \
  {                                                                            \
    _Pragma("unroll")                                                          \
    for (int kk = 0; kk < 2; ++kk) {                                           \
      bf16x8 af[4], bff[4];                                                    \
      _Pragma("unroll")                                                        \
      for (int mi = 0; mi < 4; ++mi) {                                         \
        const int row = wr * 64 + mi * 16 + l15;                               \
        af[mi] = *(const bf16x8*)&As[buf][(row * 128 + swzb(row, kk * 64 + lhi * 16)) >> 1]; \
      }                                                                        \
      _Pragma("unroll")                                                        \
      for (int ni = 0; ni < 4; ++ni) {                                         \
        const int rn = wc * 64 + ni * 16 + l15;                                \
        bff[ni] = *(const bf16x8*)&Bs[buf][(rn * 128 + swzb(rn, kk * 64 + lhi * 16)) >> 1]; \
      }                                                                        \
      _Pragma("unroll")                                                        \
      for (int mi = 0; mi < 4; ++mi)                                           \
        _Pragma("unroll")                                                      \
        for (int ni = 0; ni < 4; ++ni)                                         \
          acc[mi][ni] = __builtin_amdgcn_mfma_f32_16x16x32_bf16(af[mi], bff[ni], acc[mi][ni], 0, 0, 0); \
    }                                                                          \
  }

  STAGE(0, 0)
  __syncthreads();
#pragma unroll
  for (int kt = 0; kt < 8; ++kt) {
    if (kt < 7) STAGE((kt + 1) & 1, (kt + 1) * GBK)
    COMPUTE(kt & 1)
    __syncthreads();
  }

  float bias[4], ws0[4], ws1[4], ws2[4], wa0[4], wa1[4], wc0[4], wc1[4];
#pragma unroll
  for (int ni = 0; ni < 4; ++ni) {
    const int col = bn + wc * 64 + ni * 16 + l15;
    bias[ni] = b2[col];
    ws0[ni] = Wss[col * 3 + 0]; ws1[ni] = Wss[col * 3 + 1]; ws2[ni] = Wss[col * 3 + 2];
    wa0[ni] = Wang[col * 2 + 0]; wa1[ni] = Wang[col * 2 + 1];
    wc0[ni] = Wc[col]; wc1[ni] = Wc[HID + col];
  }
  const int slice = xblk * 2 + wc;
#pragma unroll
  for (int mi = 0; mi < 4; ++mi) {
#pragma unroll
    for (int j = 0; j < 4; ++j) {
      float p0 = 0, p1 = 0, p2 = 0, p3 = 0, p4 = 0, p5 = 0, p6 = 0;
#pragma unroll
      for (int ni = 0; ni < 4; ++ni) {
        const float v = fmaxf(acc[mi][ni][j] + bias[ni], 0.f);
        p0 += v * ws0[ni]; p1 += v * ws1[ni]; p2 += v * ws2[ni];
        p3 += v * wa0[ni]; p4 += v * wa1[ni];
        p5 += v * wc0[ni]; p6 += v * wc1[ni];
      }
#pragma unroll
      for (int m = 1; m <= 8; m <<= 1) {
        p0 += __shfl_xor(p0, m); p1 += __shfl_xor(p1, m); p2 += __shfl_xor(p2, m);
        p3 += __shfl_xor(p3, m); p4 += __shfl_xor(p4, m);
        p5 += __shfl_xor(p5, m); p6 += __shfl_xor(p6, m);
      }
      if (l15 == 0) {
        const int row = bm + wr * 64 + mi * 16 + lhi * 4 + j;
        float* hp = &Hpart[((size_t)slice * MROWS + row) * 8];
        hp[0] = p0; hp[1] = p1; hp[2] = p2; hp[3] = p3;
        hp[4] = p4; hp[5] = p5; hp[6] = p6;
      }
    }
  }
#undef STAGE
#undef COMPUTE
}

// ---------------------------------------------------------------------------
// Kernel 3 (fused): finish heads + contact. Grid 512 = 4 batches x 128
// i-tiles of 16 rows. Per block: cj for the whole batch into LDS (Hpart is
// 2 MB, L2-hot), ss/ang/ci for its 16 rows, then the 16x2048 sigmoid tile.
// Requires Hpart in d_ws (read/write race if it lived inside contact).
// ---------------------------------------------------------------------------
__global__ __launch_bounds__(256) void k_finish_contact(const float* __restrict__ Hpart,
                                                        const float* __restrict__ bss,
                                                        const float* __restrict__ bang,
                                                        const float* __restrict__ bc,
                                                        float* __restrict__ ssO,
                                                        float* __restrict__ angO,
                                                        float* __restrict__ contact) {
  __shared__ float cj_l[LSEQ];       // 8 KB
  __shared__ float ci_l[ITILE];
  const int blk = blockIdx.x;        // 0..511
  const int b   = blk >> 7;
  const int i0  = (blk & 127) * ITILE;
  const int t   = threadIdx.x;
  const size_t rowbase = (size_t)b * LSEQ;

  for (int j = t; j < LSEQ; j += 256) {
    float c = 0.f;
#pragma unroll
    for (int s = 0; s < 8; ++s)
      c += Hpart[((size_t)s * MROWS + rowbase + j) * 8 + 6];
    cj_l[j] = c;
  }
  if (t < ITILE) {
    const size_t r = rowbase + i0 + t;
    float s0 = 0, s1 = 0, s2 = 0, a0 = 0, a1 = 0, c0 = 0;
#pragma unroll
    for (int s = 0; s < 8; ++s) {
      const float* hp = &Hpart[((size_t)s * MROWS + r) * 8];
      s0 += hp[0]; s1 += hp[1]; s2 += hp[2];
      a0 += hp[3]; a1 += hp[4]; c0 += hp[5];
    }
    const float l0 = s0 + bss[0], l1 = s1 + bss[1], l2 = s2 + bss[2];
    const float mx = fmaxf(l0, fmaxf(l1, l2));
    const float e0 = __expf(l0 - mx), e1 = __expf(l1 - mx), e2 = __expf(l2 - mx);
    const float inv = 1.f / (e0 + e1 + e2);
    ssO[r * 3 + 0] = e0 * inv;
    ssO[r * 3 + 1] = e1 * inv;
    ssO[r * 3 + 2] = e2 * inv;
    angO[r * 2 + 0] = a0 + bang[0];
    angO[r * 2 + 1] = a1 + bang[1];
    ci_l[t] = c0 + bc[0];
  }
  __syncthreads();

#pragma unroll
  for (int r = 0; r < ITILE; ++r) {
    const float base = ci_l[r];
    float* orow = contact + (rowbase + i0 + r) * LSEQ;
#pragma unroll
    for (int jc = 0; jc < 2; ++jc) {
      const int j0 = jc * 1024 + t * 4;
      const float4 c4 = *(const float4*)&cj_l[j0];
      float4 o;
      o.x = 1.f / (1.f + __expf(-(base + c4.x)));
      o.y = 1.f / (1.f + __expf(-(base + c4.y)));
      o.z = 1.f / (1.f + __expf(-(base + c4.z)));
      o.w = 1.f / (1.f + __expf(-(base + c4.w)));
      *(float4*)&orow[j0] = o;
    }
  }
}

// ---------------------------------------------------------------------------
// Fallback path (ws too small): R4's separate finish + contact, Hpart in the
// contact region (safe there because contact kernel runs after finish).
// ---------------------------------------------------------------------------
__global__ __launch_bounds__(128) void k_finish(const float* __restrict__ Hpart,
                                                const float* __restrict__ bss,
                                                const float* __restrict__ bang,
                                                float* __restrict__ ssO,
                                                float* __restrict__ angO,
                                                float* __restrict__ ci,
                                                float* __restrict__ cj) {
  const int row = blockIdx.x * 128 + threadIdx.x;
  float s0 = 0, s1 = 0, s2 = 0, a0 = 0, a1 = 0, c0 = 0, c1 = 0;
#pragma unroll
  for (int xb = 0; xb < 8; ++xb) {
    const float* hp = &Hpart[((size_t)xb * MROWS + row) * 8];
    s0 += hp[0]; s1 += hp[1]; s2 += hp[2];
    a0 += hp[3]; a1 += hp[4];
    c0 += hp[5]; c1 += hp[6];
  }
  const float l0 = s0 + bss[0], l1 = s1 + bss[1], l2 = s2 + bss[2];
  const float mx = fmaxf(l0, fmaxf(l1, l2));
  const float e0 = __expf(l0 - mx), e1 = __expf(l1 - mx), e2 = __expf(l2 - mx);
  const float inv = 1.f / (e0 + e1 + e2);
  ssO[row * 3 + 0] = e0 * inv;
  ssO[row * 3 + 1] = e1 * inv;
  ssO[row * 3 + 2] = e2 * inv;
  angO[row * 2 + 0] = a0 + bang[0];
  angO[row * 2 + 1] = a1 + bang[1];
  ci[row] = c0;
  cj[row] = c1;
}

__global__ __launch_bounds__(256) void k_contact(const float* __restrict__ ci,
                                                 const float* __restrict__ cj,
                                                 const float* __restrict__ bc,
                                                 float* __restrict__ out) {
  const int row = blockIdx.x;
  const int b   = row >> 11;
  const float base = ci[row] + bc[0];
  const float* cjb = cj + ((size_t)b << 11);
  float* orow = out + (size_t)row * LSEQ;
  const int j0 = threadIdx.x * 8;
  const float4 c0 = *(const float4*)&cjb[j0];
  const float4 c1 = *(const float4*)&cjb[j0 + 4];
  float4 r0, r1;
  r0.x = 1.f / (1.f + __expf(-(base + c0.x)));
  r0.y = 1.f / (1.f + __expf(-(base + c0.y)));
  r0.z = 1.f / (1.f + __expf(-(base + c0.z)));
  r0.w = 1.f / (1.f + __expf(-(base + c0.w)));
  r1.x = 1.f / (1.f + __expf(-(base + c1.x)));
  r1.y = 1.f / (1.f + __expf(-(base + c1.y)));
  r1.z = 1.f / (1.f + __expf(-(base + c1.z)));
  r1.w = 1.f / (1.f + __expf(-(base + c1.w)));
  *(float4*)&orow[j0]     = r0;
  *(float4*)&orow[j0 + 4] = r1;
}

// ---------------------------------------------------------------------------
extern "C" void kernel_launch(void* const* d_in, const int* in_sizes, int n_in,
                              void* d_out, int out_size, void* d_ws, size_t ws_size,
                              hipStream_t stream) {
  const float* X    = (const float*)d_in[0];
  const float* W1   = (const float*)d_in[1];
  const float* b1   = (const float*)d_in[2];
  const float* W2   = (const float*)d_in[3];
  const float* b2   = (const float*)d_in[4];
  const float* Wss  = (const float*)d_in[5];
  const float* bss  = (const float*)d_in[6];
  const float* Wang = (const float*)d_in[7];
  const float* bang = (const float*)d_in[8];
  const float* Wc   = (const float*)d_in[9];
  const float* bc   = (const float*)d_in[10];

  float* out     = (float*)d_out;
  float* ssO     = out;                         // [8192,3]
  float* angO    = out + 24576;                 // [8192,2]
  float* contact = out + 40960;                 // [4,2048,2048] = 64MB

  // h1/W2t scratch inside the not-yet-written contact region (fully
  // overwritten by the contact pass, which runs last).
  ushort* h1  = (ushort*)contact;                        // 8 MB  (swizzled)
  ushort* W2t = (ushort*)(contact + 2 * 1024 * 1024);    // 512 KB (swizzled)

  k_prep<<<768, 256, 0, stream>>>(X, W1, b1, W2, h1, W2t);

  if (ws_size >= (size_t)HPART_FLOATS * 4) {
    // 3-kernel path: Hpart in d_ws (fused finish+contact READS Hpart while
    // WRITING contact, so Hpart must not alias the contact region).
    float* Hpart = (float*)d_ws;
    k_gemm_heads<<<256, 256, 0, stream>>>(h1, W2t, b2, Wss, Wang, Wc, Hpart);
    k_finish_contact<<<512, 256, 0, stream>>>(Hpart, bss, bang, bc,
                                              ssO, angO, contact);
  } else {
    // Fallback (R4 flow): Hpart in contact region, separate finish+contact.
    float* Hpart = contact + 3 * 1024 * 1024;
    float* ci = (float*)d_ws;
    float* cj = ci + MROWS;
    k_gemm_heads<<<256, 256, 0, stream>>>(h1, W2t, b2, Wss, Wang, Wc, Hpart);
    k_finish<<<MROWS / 128, 128, 0, stream>>>(Hpart, bss, bang, ssO, angO, ci, cj);
    k_contact<<<MROWS, 256, 0, stream>>>(ci, cj, bc, contact);
  }
}

// Round 7
// 46.029 us; speedup vs baseline: 1.2588x; 1.2588x over previous
//
#include <hip/hip_runtime.h>
#include <cstdint>
#include <cstddef>

#define SEQD 20
#define HID  512
#define LSEQ 2048
#define MROWS 8192
#define GBM 128
#define GBN 128
#define GBK 64
#define ITILE 8
#define ACC_FLOATS (6 * MROWS + MROWS)   // acc6[8192][6] + cjacc[8192] = 57344

typedef __attribute__((ext_vector_type(4))) float f32x4;
typedef __attribute__((ext_vector_type(8))) short bf16x8;

__device__ __forceinline__ ushort f2bf(float f) {
  union { float f; unsigned u; } v; v.f = f;
  unsigned r = v.u + 0x7fffu + ((v.u >> 16) & 1u);   // RNE
  return (ushort)(r >> 16);
}
// XOR-swizzle of byte offset b (0..127) within a 128B k-stripe, keyed by row.
// Involution on 16B-slot bits (4..6). Applied at global write (pre-swizzle)
// and at ds_read; LDS staging copies linearly (rule #21).
__device__ __forceinline__ int swzb(int row, int b) {
  return (b & 0x0F) | ((b ^ ((row & 7) << 4)) & 0x70);
}
// async global->LDS, 16B/lane. lds ptr wave-uniform (HW adds lane*16).
__device__ __forceinline__ void async16(const ushort* g, ushort* l) {
  __builtin_amdgcn_global_load_lds(
      (const __attribute__((address_space(1))) unsigned*)g,
      (__attribute__((address_space(3))) unsigned*)l, 16, 0, 0);
}

// ---------------------------------------------------------------------------
// Kernel 1 (prep): blocks [0,512): h1 = relu(X@W1+b1) -> bf16, PRE-SWIZZLED.
//                  blocks [512,768): W2t transpose (PRE-SWIZZLED) + zero the
//                  224KB head-accumulator region in ws (must precede gemm's
//                  atomics; re-zeroed every launch for graph replay).
// ---------------------------------------------------------------------------
__global__ __launch_bounds__(256) void k_prep(const float* __restrict__ X,
                                              const float* __restrict__ W1,
                                              const float* __restrict__ b1,
                                              const float* __restrict__ W2,
                                              ushort* __restrict__ h1,
                                              ushort* __restrict__ W2t,
                                              float* __restrict__ accws) {
  __shared__ float Xs[16][SEQD + 1];
  __shared__ float tile[32][33];
  const int t = threadIdx.x;
  if (blockIdx.x < 512) {
    const int base = blockIdx.x * 16;
    for (int i = t; i < 16 * SEQD; i += 256) Xs[i / SEQD][i % SEQD] = X[base * SEQD + i];
    __syncthreads();
    const int m0 = (t >> 6) * 4;
    const int nl = (t & 63) * 4;
    float4 acc[4][2];
#pragma unroll
    for (int mi = 0; mi < 4; ++mi) {
      acc[mi][0] = *(const float4*)&b1[nl];
      acc[mi][1] = *(const float4*)&b1[nl + 256];
    }
#pragma unroll
    for (int k = 0; k < SEQD; ++k) {
      const float4 w0 = *(const float4*)&W1[k * HID + nl];
      const float4 w1 = *(const float4*)&W1[k * HID + nl + 256];
#pragma unroll
      for (int mi = 0; mi < 4; ++mi) {
        const float xv = Xs[m0 + mi][k];
        acc[mi][0].x += xv * w0.x; acc[mi][0].y += xv * w0.y;
        acc[mi][0].z += xv * w0.z; acc[mi][0].w += xv * w0.w;
        acc[mi][1].x += xv * w1.x; acc[mi][1].y += xv * w1.y;
        acc[mi][1].z += xv * w1.z; acc[mi][1].w += xv * w1.w;
      }
    }
#pragma unroll
    for (int mi = 0; mi < 4; ++mi) {
      const int m = base + m0 + mi;
#pragma unroll
      for (int g = 0; g < 2; ++g) {
        const float4 r = acc[mi][g];
        ushort4 o;
        o.x = f2bf(fmaxf(r.x, 0.f)); o.y = f2bf(fmaxf(r.y, 0.f));
        o.z = f2bf(fmaxf(r.z, 0.f)); o.w = f2bf(fmaxf(r.w, 0.f));
        const int k = nl + g * 256;
        const int sb = swzb(m, (k & 63) * 2);
        *(ushort4*)&h1[(size_t)m * HID + (k & ~63) + (sb >> 1)] = o;
      }
    }
  } else {
    // zero head accumulators: 57344 floats over 256 blocks x 256 threads
    const int zi = (blockIdx.x - 512) * 256 + t;
    if (zi < ACC_FLOATS) accws[zi] = 0.f;

    const int c = blockIdx.x - 512;
    const int k0 = (c & 15) * 32, n0 = (c >> 4) * 32;
    const int tx = t & 31, ty = t >> 5;
#pragma unroll
    for (int r = ty; r < 32; r += 8)
      tile[r][tx] = W2[(size_t)(k0 + r) * HID + n0 + tx];
    __syncthreads();
#pragma unroll
    for (int r = ty; r < 32; r += 8) {
      const int n = n0 + r, k = k0 + tx;
      const int sb = swzb(n, (k & 63) * 2);
      W2t[(size_t)n * HID + (k & ~63) + (sb >> 1)] = f2bf(tile[tx][r]);
    }
  }
}

// ---------------------------------------------------------------------------
// Kernel 2: gemm2 + fused heads — R4's exact GEMM config (best measured:
// BM=BN=128, BK=64, grid 256, 4 waves 2x2, 2-phase dbuf global_load_lds).
// Epilogue: wc-pair LDS combine, then per-row atomicAdd into acc6 (ss0..2,
// a0,a1,ci; [8192][6]) and cjacc ([8192], CONTIGUOUS so the consumer reads
// densely — R6's regression was a strided re-reduction of cj per block).
// ---------------------------------------------------------------------------
__global__ __launch_bounds__(256) void k_gemm_heads(const ushort* __restrict__ Aglob,
                                                    const ushort* __restrict__ Bglob,
                                                    const float* __restrict__ b2,
                                                    const float* __restrict__ Wss,
                                                    const float* __restrict__ Wang,
                                                    const float* __restrict__ Wc,
                                                    float* __restrict__ acc6,
                                                    float* __restrict__ cjacc) {
  __shared__ ushort As[2][GBM * GBK];
  __shared__ ushort Bs[2][GBM * GBK];
  __shared__ float  comb[2][GBM][8];
  const int t = threadIdx.x;
  const int wave = t >> 6, lane = t & 63;
  const int l15 = lane & 15, lhi = lane >> 4;
  const int wr = wave >> 1, wc = wave & 1;
  const int swz = (blockIdx.x & 7) * 32 + (blockIdx.x >> 3);  // bijective, 256%8==0
  const int xblk = swz & 3, yblk = swz >> 2;
  const int bm = yblk * GBM, bn = xblk * GBN;
  const int srow = lane >> 3;
  const int scol = (lane & 7) * 8;

  f32x4 acc[4][4];
#pragma unroll
  for (int mi = 0; mi < 4; ++mi)
#pragma unroll
    for (int ni = 0; ni < 4; ++ni) acc[mi][ni] = {0.f, 0.f, 0.f, 0.f};

#define STAGE(buf, k0)                                                         \
  {                                                                            \
    _Pragma("unroll")                                                          \
    for (int rd = 0; rd < 4; ++rd) {                                           \
      const int r = rd * 32 + wave * 8 + srow;                                 \
      const int lo = rd * 2048 + wave * 512;                                   \
      async16(Aglob + (size_t)(bm + r) * HID + (k0) + scol, &As[buf][lo]);     \
      async16(Bglob + (size_t)(bn + r) * HID + (k0) + scol, &Bs[buf][lo]);     \
    }                                                                          \
  }

#define COMPUTE(buf)                                                           \
  {                                                                            \
    _Pragma("unroll")                                                          \
    for (int kk = 0; kk < 2; ++kk) {                                           \
      bf16x8 af[4], bff[4];                                                    \
      _Pragma("unroll")                                                        \
      for (int mi = 0; mi < 4; ++mi) {                                         \
        const int row = wr * 64 + mi * 16 + l15;                               \
        af[mi] = *(const bf16x8*)&As[buf][(row * 128 + swzb(row, kk * 64 + lhi * 16)) >> 1]; \
      }                                                                        \
      _Pragma("unroll")                                                        \
      for (int ni = 0; ni < 4; ++ni) {                                         \
        const int rn = wc * 64 + ni * 16 + l15;                                \
        bff[ni] = *(const bf16x8*)&Bs[buf][(rn * 128 + swzb(rn, kk * 64 + lhi * 16)) >> 1]; \
      }                                                                        \
      _Pragma("unroll")                                                        \
      for (int mi = 0; mi < 4; ++mi)                                           \
        _Pragma("unroll")                                                      \
        for (int ni = 0; ni < 4; ++ni)                                         \
          acc[mi][ni] = __builtin_amdgcn_mfma_f32_16x16x32_bf16(af[mi], bff[ni], acc[mi][ni], 0, 0, 0); \
    }                                                                          \
  }

  STAGE(0, 0)
  __syncthreads();
#pragma unroll
  for (int kt = 0; kt < 8; ++kt) {
    if (kt < 7) STAGE((kt + 1) & 1, (kt + 1) * GBK)
    COMPUTE(kt & 1)
    __syncthreads();
  }

  // ---- epilogue ----
  float bias[4], ws0[4], ws1[4], ws2[4], wa0[4], wa1[4], wc0[4], wc1[4];
#pragma unroll
  for (int ni = 0; ni < 4; ++ni) {
    const int col = bn + wc * 64 + ni * 16 + l15;
    bias[ni] = b2[col];
    ws0[ni] = Wss[col * 3 + 0]; ws1[ni] = Wss[col * 3 + 1]; ws2[ni] = Wss[col * 3 + 2];
    wa0[ni] = Wang[col * 2 + 0]; wa1[ni] = Wang[col * 2 + 1];
    wc0[ni] = Wc[col]; wc1[ni] = Wc[HID + col];
  }
#pragma unroll
  for (int mi = 0; mi < 4; ++mi) {
#pragma unroll
    for (int j = 0; j < 4; ++j) {
      float p0 = 0, p1 = 0, p2 = 0, p3 = 0, p4 = 0, p5 = 0, p6 = 0;
#pragma unroll
      for (int ni = 0; ni < 4; ++ni) {
        const float v = fmaxf(acc[mi][ni][j] + bias[ni], 0.f);
        p0 += v * ws0[ni]; p1 += v * ws1[ni]; p2 += v * ws2[ni];
        p3 += v * wa0[ni]; p4 += v * wa1[ni];
        p5 += v * wc0[ni]; p6 += v * wc1[ni];
      }
#pragma unroll
      for (int m = 1; m <= 8; m <<= 1) {
        p0 += __shfl_xor(p0, m); p1 += __shfl_xor(p1, m); p2 += __shfl_xor(p2, m);
        p3 += __shfl_xor(p3, m); p4 += __shfl_xor(p4, m);
        p5 += __shfl_xor(p5, m); p6 += __shfl_xor(p6, m);
      }
      if (l15 == 0) {
        const int lr = wr * 64 + mi * 16 + lhi * 4 + j;   // local row 0..127
        comb[wc][lr][0] = p0; comb[wc][lr][1] = p1; comb[wc][lr][2] = p2;
        comb[wc][lr][3] = p3; comb[wc][lr][4] = p4;
        comb[wc][lr][5] = p5; comb[wc][lr][6] = p6;
      }
    }
  }
  __syncthreads();
  if (t < GBM) {
    const int row = bm + t;
#pragma unroll
    for (int q = 0; q < 6; ++q)
      atomicAdd(&acc6[(size_t)row * 6 + q], comb[0][t][q] + comb[1][t][q]);
    atomicAdd(&cjacc[row], comb[0][t][6] + comb[1][t][6]);
  }
#undef STAGE
#undef COMPUTE
}

// ---------------------------------------------------------------------------
// Kernel 3: finalize + contact. Grid 1024 = 4 batches x 256 tiles of 8 rows.
// Dense float4 read of the batch's cjacc (8KB -> LDS), t<8 finalize ss/ang/ci
// for this tile's rows, then the 8x2048 sigmoid tile (64KB write).
// ---------------------------------------------------------------------------
__global__ __launch_bounds__(256) void k_fc(const float* __restrict__ acc6,
                                            const float* __restrict__ cjacc,
                                            const float* __restrict__ bss,
                                            const float* __restrict__ bang,
                                            const float* __restrict__ bc,
                                            float* __restrict__ ssO,
                                            float* __restrict__ angO,
                                            float* __restrict__ contact) {
  __shared__ float cj_l[LSEQ];
  __shared__ float ci_l[ITILE];
  const int blk = blockIdx.x;            // 0..1023
  const int b   = blk >> 8;              // batch
  const int i0  = (blk & 255) * ITILE;
  const int t   = threadIdx.x;
  const size_t rowbase = (size_t)b * LSEQ;

  {
    const float* cjb = cjacc + rowbase;
#pragma unroll
    for (int it = 0; it < 2; ++it) {
      const int j = it * 1024 + t * 4;
      *(float4*)&cj_l[j] = *(const float4*)&cjb[j];
    }
  }
  if (t < ITILE) {
    const size_t r = rowbase + i0 + t;
    const float* a = &acc6[r * 6];
    const float l0 = a[0] + bss[0], l1 = a[1] + bss[1], l2 = a[2] + bss[2];
    const float mx = fmaxf(l0, fmaxf(l1, l2));
    const float e0 = __expf(l0 - mx), e1 = __expf(l1 - mx), e2 = __expf(l2 - mx);
    const float inv = 1.f / (e0 + e1 + e2);
    ssO[r * 3 + 0] = e0 * inv;
    ssO[r * 3 + 1] = e1 * inv;
    ssO[r * 3 + 2] = e2 * inv;
    angO[r * 2 + 0] = a[3] + bang[0];
    angO[r * 2 + 1] = a[4] + bang[1];
    ci_l[t] = a[5] + bc[0];
  }
  __syncthreads();

#pragma unroll
  for (int r = 0; r < ITILE; ++r) {
    const float base = ci_l[r];
    float* orow = contact + (rowbase + i0 + r) * LSEQ;
#pragma unroll
    for (int jc = 0; jc < 2; ++jc) {
      const int j0 = jc * 1024 + t * 4;
      const float4 c4 = *(const float4*)&cj_l[j0];
      float4 o;
      o.x = 1.f / (1.f + __expf(-(base + c4.x)));
      o.y = 1.f / (1.f + __expf(-(base + c4.y)));
      o.z = 1.f / (1.f + __expf(-(base + c4.z)));
      o.w = 1.f / (1.f + __expf(-(base + c4.w)));
      *(float4*)&orow[j0] = o;
    }
  }
}

// ---------------------------------------------------------------------------
extern "C" void kernel_launch(void* const* d_in, const int* in_sizes, int n_in,
                              void* d_out, int out_size, void* d_ws, size_t ws_size,
                              hipStream_t stream) {
  const float* X    = (const float*)d_in[0];
  const float* W1   = (const float*)d_in[1];
  const float* b1   = (const float*)d_in[2];
  const float* W2   = (const float*)d_in[3];
  const float* b2   = (const float*)d_in[4];
  const float* Wss  = (const float*)d_in[5];
  const float* bss  = (const float*)d_in[6];
  const float* Wang = (const float*)d_in[7];
  const float* bang = (const float*)d_in[8];
  const float* Wc   = (const float*)d_in[9];
  const float* bc   = (const float*)d_in[10];

  float* out     = (float*)d_out;
  float* ssO     = out;                         // [8192,3]
  float* angO    = out + 24576;                 // [8192,2]
  float* contact = out + 40960;                 // [4,2048,2048] = 64MB

  // h1/W2t scratch inside the not-yet-written contact region (fully
  // overwritten by k_fc, which runs last and reads only ws + biases).
  ushort* h1  = (ushort*)contact;                        // 8 MB  (swizzled)
  ushort* W2t = (ushort*)(contact + 2 * 1024 * 1024);    // 512 KB (swizzled)

  // ws layout: acc6[8192][6] | cjacc[8192]  (224 KB; ws >= 2MB per R6 run)
  float* acc6  = (float*)d_ws;
  float* cjacc = acc6 + (size_t)6 * MROWS;

  k_prep<<<768, 256, 0, stream>>>(X, W1, b1, W2, h1, W2t, acc6);
  k_gemm_heads<<<256, 256, 0, stream>>>(h1, W2t, b2, Wss, Wang, Wc, acc6, cjacc);
  k_fc<<<1024, 256, 0, stream>>>(acc6, cjacc, bss, bang, bc, ssO, angO, contact);
}